// Round 4
// baseline (200.075 us; speedup 1.0000x reference)
//
#include <hip/hip_runtime.h>
#include <cstddef>

typedef _Float16 half8 __attribute__((ext_vector_type(8)));
typedef __fp16 fp16x2 __attribute__((ext_vector_type(2)));
typedef float f32x4 __attribute__((ext_vector_type(4)));

// Problem constants: B=8, T=2048, D=1024, H=64
// Workspace layout (bytes):
//   Wt  (f16, [192][1024], W^T concat q|k|v):      0
//   q   (f16, [16384][64], pre-scaled by 0.125*log2e)
//   k   (f16, [16384][64], rows INTERLEAVED within 32-blocks: even keys 0..15, odd 16..31)
//   vT  (f16, [8][64][2048])
#define WT_OFF 0
#define Q_OFF  393216
#define K_OFF  2490368
#define V_OFF  4587520

// ---------------------------------------------------------------------------
// Kernel 1: convert Wq|Wk|Wv (each [1024][64] fp32) into transposed f16 Wt[c][d]
__global__ __launch_bounds__(256) void wcvt_kernel(const float* __restrict__ wq,
                                                   const float* __restrict__ wk,
                                                   const float* __restrict__ wv,
                                                   _Float16* __restrict__ wt) {
  int idx = blockIdx.x * 256 + threadIdx.x;  // idx = c*1024 + d, 196608 total
  int c = idx >> 10;
  int d = idx & 1023;
  float v;
  if (c < 64)       v = wq[d * 64 + c];
  else if (c < 128) v = wk[d * 64 + (c - 64)];
  else              v = wv[d * 64 + (c - 128)];
  wt[idx] = (_Float16)v;
}

// ---------------------------------------------------------------------------
// Kernel 2: QKV projection, barrier-free, register-pipelined.
// 1024 blocks x 256 thr (4 waves). Block = one 16-row strip; wave w covers cols
// w*48..w*48+47 (3 MFMA tiles). A loaded direct from global x with depth-4
// register prefetch; B (Wt) depth-2. No LDS, no __syncthreads.
__global__ __launch_bounds__(256, 4) void qkv_kernel(const float* __restrict__ x,
                                                     const _Float16* __restrict__ wt,
                                                     _Float16* __restrict__ qws,
                                                     _Float16* __restrict__ kws,
                                                     _Float16* __restrict__ vtws) {
  const int tid = threadIdx.x;
  const int wave = tid >> 6;
  const int lane = tid & 63;
  const int quad = lane >> 4;
  const int ln = lane & 15;
  const int t0 = blockIdx.x * 16;

  f32x4 acc[3];
#pragma unroll
  for (int n = 0; n < 3; ++n) acc[n] = (f32x4){0.f, 0.f, 0.f, 0.f};

  const float* xrow = x + (size_t)(t0 + ln) * 1024 + quad * 8;
  const _Float16* wb = wt + (size_t)(wave * 48 + ln) * 1024 + quad * 8;

  // A prefetch depth 4 (steps of 32 floats in k)
  float4 plo[4], phi[4];
#pragma unroll
  for (int i = 0; i < 4; ++i) {
    plo[i] = *(const float4*)(xrow + i * 32);
    phi[i] = *(const float4*)(xrow + i * 32 + 4);
  }
  // B prefetch depth 2
  half8 bbuf[2][3];
#pragma unroll
  for (int n = 0; n < 3; ++n) bbuf[0][n] = *(const half8*)(wb + (size_t)n * 16384);

#pragma unroll
  for (int s = 0; s < 32; ++s) {
    const float4 lo = plo[s & 3];
    const float4 hi = phi[s & 3];
    if (s < 28) {
      plo[s & 3] = *(const float4*)(xrow + (s + 4) * 32);
      phi[s & 3] = *(const float4*)(xrow + (s + 4) * 32 + 4);
    }
    if (s < 31) {
#pragma unroll
      for (int n = 0; n < 3; ++n)
        bbuf[(s + 1) & 1][n] = *(const half8*)(wb + (size_t)n * 16384 + (s + 1) * 32);
    }
    union { _Float16 h[8]; half8 v; } a;
    a.h[0] = (_Float16)lo.x; a.h[1] = (_Float16)lo.y;
    a.h[2] = (_Float16)lo.z; a.h[3] = (_Float16)lo.w;
    a.h[4] = (_Float16)hi.x; a.h[5] = (_Float16)hi.y;
    a.h[6] = (_Float16)hi.z; a.h[7] = (_Float16)hi.w;
#pragma unroll
    for (int n = 0; n < 3; ++n)
      acc[n] = __builtin_amdgcn_mfma_f32_16x16x32_f16(a.v, bbuf[s & 1][n], acc[n], 0, 0, 0);
  }

  // Epilogue: C/D layout row = quad*4+r, col = ln (within tile n)
  const int trow0 = t0 + quad * 4;
#pragma unroll
  for (int n = 0; n < 3; ++n) {
    const int c = wave * 48 + n * 16 + ln;
    if (c < 64) {
#pragma unroll
      for (int r = 0; r < 4; ++r)
        qws[(size_t)(trow0 + r) * 64 + c] = (_Float16)(acc[n][r] * 0.18033688011112042f);
    } else if (c < 128) {
      // interleaved K rows: within each 32-block, even keys -> 0..15, odd -> 16..31
#pragma unroll
      for (int r = 0; r < 4; ++r) {
        const int t = trow0 + r;
        const int pos = (t & ~31) | (((t & 31) >> 1) + ((t & 1) << 4));
        kws[(size_t)pos * 64 + (c - 64)] = (_Float16)acc[n][r];
      }
    } else {
      const int h = c - 128;
      const int bb = trow0 >> 11;   // batch
      const int ti = trow0 & 2047;  // t within batch (multiple of 4)
      union { _Float16 h4[4]; short4 s; } u;
#pragma unroll
      for (int r = 0; r < 4; ++r) u.h4[r] = (_Float16)acc[n][r];
      *(short4*)&vtws[(size_t)(bb * 64 + h) * 2048 + ti] = u.s;
    }
  }
}

// ---------------------------------------------------------------------------
// Kernel 3: causal flash attention, fixed-max softmax (p = exp2(S-12)).
// 1024 blocks = (tile, batch), 256 thr = 4 waves; keys split 4 ways; K/V
// fragments prefetched one j ahead; packed P stores (K interleaved layout).
__global__ __launch_bounds__(256) void attn_kernel(const _Float16* __restrict__ qws,
                                                   const _Float16* __restrict__ kws,
                                                   const _Float16* __restrict__ vtws,
                                                   float* __restrict__ out) {
  __shared__ __align__(16) _Float16 plds[4 * 16 * 40];  // per-wave P tile (80B/row pad)
  __shared__ __align__(16) float Olds[4 * 16 * 64];
  __shared__ float llds[4 * 16];

  const int tid = threadIdx.x;
  const int wave = tid >> 6;
  const int lane = tid & 63;
  const int quad = lane >> 4;
  const int ln = lane & 15;
  const int tile = 127 - (blockIdx.x >> 3);  // biggest tiles dispatch first
  const int b = blockIdx.x & 7;
  const int t0 = tile * 16;
  const size_t bb = (size_t)b * 2048;
  _Float16* myp = plds + wave * 640;

  const float NEG_INF = -__builtin_inff();

  // key blocks of 32 covering keys 0..t0+15, split balanced across 4 waves
  const int nkb = (t0 + 47) >> 5;
  const int base = nkb >> 2;
  const int rem = nkb & 3;
  const int jb = wave * base + (wave < rem ? wave : rem);
  const int je = jb + base + (wave < rem ? 1 : 0);

  // Q fragments (A-operand): row m = ln, k = h
  const _Float16* qrow = qws + (bb + t0 + ln) * 64;
  half8 qf0 = *(const half8*)(qrow + quad * 8);
  half8 qf1 = *(const half8*)(qrow + 32 + quad * 8);

  float l[4] = {0.f, 0.f, 0.f, 0.f};
  f32x4 O[4];
#pragma unroll
  for (int h = 0; h < 4; ++h) O[h] = (f32x4){0.f, 0.f, 0.f, 0.f};

  const _Float16* kbase = kws + (bb + (size_t)jb * 32) * 64;
  const _Float16* vbase = vtws + (size_t)b * 131072 + jb * 32;
  half8 kf0, kf1, kf2, kf3, vf0, vf1, vf2, vf3;
  if (jb < je) {
    kf0 = *(const half8*)(kbase + ln * 64 + quad * 8);
    kf1 = *(const half8*)(kbase + ln * 64 + 32 + quad * 8);
    kf2 = *(const half8*)(kbase + (16 + ln) * 64 + quad * 8);
    kf3 = *(const half8*)(kbase + (16 + ln) * 64 + 32 + quad * 8);
    vf0 = *(const half8*)(vbase + (size_t)(ln) * 2048 + quad * 8);
    vf1 = *(const half8*)(vbase + (size_t)(16 + ln) * 2048 + quad * 8);
    vf2 = *(const half8*)(vbase + (size_t)(32 + ln) * 2048 + quad * 8);
    vf3 = *(const half8*)(vbase + (size_t)(48 + ln) * 2048 + quad * 8);
  }

  for (int j = jb; j < je; ++j) {
    const int k0 = j << 5;
    f32x4 S0 = (f32x4){0.f, 0.f, 0.f, 0.f};
    f32x4 S1 = (f32x4){0.f, 0.f, 0.f, 0.f};
    S0 = __builtin_amdgcn_mfma_f32_16x16x32_f16(qf0, kf0, S0, 0, 0, 0);
    S0 = __builtin_amdgcn_mfma_f32_16x16x32_f16(qf1, kf1, S0, 0, 0, 0);
    S1 = __builtin_amdgcn_mfma_f32_16x16x32_f16(qf0, kf2, S1, 0, 0, 0);
    S1 = __builtin_amdgcn_mfma_f32_16x16x32_f16(qf1, kf3, S1, 0, 0, 0);

    // prefetch next K block while softmax runs
    if (j + 1 < je) {
      kbase += 2048;
      kf0 = *(const half8*)(kbase + ln * 64 + quad * 8);
      kf1 = *(const half8*)(kbase + ln * 64 + 32 + quad * 8);
      kf2 = *(const half8*)(kbase + (16 + ln) * 64 + quad * 8);
      kf3 = *(const half8*)(kbase + (16 + ln) * 64 + 32 + quad * 8);
    }

    // S0 col ln = key k0+2*ln (even), S1 col ln = key k0+2*ln+1 (odd)
    if (k0 + 31 > t0) {
      const int key0 = k0 + 2 * ln;
#pragma unroll
      for (int r = 0; r < 4; ++r) {
        const int tq = t0 + quad * 4 + r;
        if (key0 > tq) S0[r] = NEG_INF;
        if (key0 + 1 > tq) S1[r] = NEG_INF;
      }
    }

#pragma unroll
    for (int r = 0; r < 4; ++r) {
      const float p0 = exp2f(S0[r] - 12.f);
      const float p1 = exp2f(S1[r] - 12.f);
      l[r] += p0 + p1;
      const int prow = quad * 4 + r;
      union { fp16x2 v; unsigned u; } pk;
      pk.v = __builtin_amdgcn_cvt_pkrtz(p0, p1);  // keys 2ln, 2ln+1
      *(unsigned*)&myp[prow * 40 + 2 * ln] = pk.u;
    }

    // P as A-operand: A[m=ln][k=quad*8+j] (wave-private LDS, in-order DS pipe)
    half8 pfr = *(const half8*)(myp + ln * 40 + quad * 8);
    O[0] = __builtin_amdgcn_mfma_f32_16x16x32_f16(pfr, vf0, O[0], 0, 0, 0);
    O[1] = __builtin_amdgcn_mfma_f32_16x16x32_f16(pfr, vf1, O[1], 0, 0, 0);
    O[2] = __builtin_amdgcn_mfma_f32_16x16x32_f16(pfr, vf2, O[2], 0, 0, 0);
    O[3] = __builtin_amdgcn_mfma_f32_16x16x32_f16(pfr, vf3, O[3], 0, 0, 0);

    if (j + 1 < je) {
      vbase += 32;
      vf0 = *(const half8*)(vbase + (size_t)(ln) * 2048 + quad * 8);
      vf1 = *(const half8*)(vbase + (size_t)(16 + ln) * 2048 + quad * 8);
      vf2 = *(const half8*)(vbase + (size_t)(32 + ln) * 2048 + quad * 8);
      vf3 = *(const half8*)(vbase + (size_t)(48 + ln) * 2048 + quad * 8);
    }
  }

  // reduce l across the 16 ln-lanes of each quad
#pragma unroll
  for (int r = 0; r < 4; ++r) {
    l[r] += __shfl_xor(l[r], 1);
    l[r] += __shfl_xor(l[r], 2);
    l[r] += __shfl_xor(l[r], 4);
    l[r] += __shfl_xor(l[r], 8);
  }

  // dump partials to LDS
#pragma unroll
  for (int r = 0; r < 4; ++r) {
    const int row = quad * 4 + r;
    if (ln == 0) llds[wave * 16 + row] = l[r];
#pragma unroll
    for (int h = 0; h < 4; ++h)
      Olds[wave * 1024 + row * 64 + h * 16 + ln] = O[h][r];
  }
  __syncthreads();

  // final 4-way sum + normalize + write: thread t -> row t>>4, cols (t&15)*4..+3
  {
    const int row = tid >> 4;
    const int col0 = (tid & 15) * 4;
    f32x4 s = (f32x4){0.f, 0.f, 0.f, 0.f};
    float ls = 0.f;
#pragma unroll
    for (int w = 0; w < 4; ++w) {
      s += *(const f32x4*)&Olds[w * 1024 + row * 64 + col0];
      ls += llds[w * 16 + row];
    }
    const float inv = 1.0f / ls;
    float4 o;
    o.x = s[0] * inv; o.y = s[1] * inv; o.z = s[2] * inv; o.w = s[3] * inv;
    *(float4*)&out[(bb + t0 + row) * 64 + col0] = o;
  }
}

// ---------------------------------------------------------------------------
extern "C" void kernel_launch(void* const* d_in, const int* in_sizes, int n_in,
                              void* d_out, int out_size, void* d_ws, size_t ws_size,
                              hipStream_t stream) {
  const float* x  = (const float*)d_in[0];
  const float* wq = (const float*)d_in[1];
  const float* wk = (const float*)d_in[2];
  const float* wv = (const float*)d_in[3];

  char* ws = (char*)d_ws;
  _Float16* wt   = (_Float16*)(ws + WT_OFF);
  _Float16* qws  = (_Float16*)(ws + Q_OFF);
  _Float16* kws  = (_Float16*)(ws + K_OFF);
  _Float16* vtws = (_Float16*)(ws + V_OFF);
  float* outp = (float*)d_out;

  wcvt_kernel<<<768, 256, 0, stream>>>(wq, wk, wv, wt);
  qkv_kernel<<<1024, 256, 0, stream>>>(x, wt, qws, kws, vtws);
  attn_kernel<<<1024, 256, 0, stream>>>(qws, kws, vtws, outp);
}

// Round 5
// 152.776 us; speedup vs baseline: 1.3096x; 1.3096x over previous
//
#include <hip/hip_runtime.h>
#include <cstddef>

typedef _Float16 half8 __attribute__((ext_vector_type(8)));
typedef __fp16 fp16x2 __attribute__((ext_vector_type(2)));
typedef float f32x4 __attribute__((ext_vector_type(4)));

// Problem constants: B=8, T=2048, D=1024, H=64
// Workspace layout (bytes):
//   Wt  (f16, [192][1024], W^T concat q|k|v):      0
//   q   (f16, [16384][64], pre-scaled by 0.125*log2e)
//   k   (f16, [16384][64], rows INTERLEAVED within 32-blocks: even keys 0..15, odd 16..31)
//   vT  (f16, [8][64][2048])
#define WT_OFF 0
#define Q_OFF  393216
#define K_OFF  2490368
#define V_OFF  4587520

__device__ __forceinline__ void glds16(const void* g, const void* l) {
  __builtin_amdgcn_global_load_lds(
      (const __attribute__((address_space(1))) unsigned*)g,
      (__attribute__((address_space(3))) unsigned*)l, 16, 0, 0);
}

// ---------------------------------------------------------------------------
// Kernel 1: convert Wq|Wk|Wv (each [1024][64] fp32) into transposed f16 Wt[c][d]
__global__ __launch_bounds__(256) void wcvt_kernel(const float* __restrict__ wq,
                                                   const float* __restrict__ wk,
                                                   const float* __restrict__ wv,
                                                   _Float16* __restrict__ wt) {
  int idx = blockIdx.x * 256 + threadIdx.x;  // idx = c*1024 + d, 196608 total
  int c = idx >> 10;
  int d = idx & 1023;
  float v;
  if (c < 64)       v = wq[d * 64 + c];
  else if (c < 128) v = wk[d * 64 + (c - 64)];
  else              v = wv[d * 64 + (c - 128)];
  wt[idx] = (_Float16)v;
}

// ---------------------------------------------------------------------------
// Kernel 2: QKV projection, m97-style. C[16384x192] = x[16384x1024]*W[1024x192].
// 512 blocks x 256 thr (4 waves). BM=32 rows/block, BN=192 (full), BK=64.
// A (fp32 x) and B (f16 Wt) staged via global_load_lds width=16 into
// XOR-swizzled LDS (16B units; pos = chunk ^ (row&15) / ^(n&7)) so the
// fragment ds_read_b128s hit the 8-words/bank floor. fp32->f16 at frag read.
// Wave w: rows 0..31 (2 m-tiles) x cols w*48..w*48+47 (3 n-tiles).
__global__ __launch_bounds__(256, 2) void qkv_kernel(const float* __restrict__ x,
                                                     const _Float16* __restrict__ wt,
                                                     _Float16* __restrict__ qws,
                                                     _Float16* __restrict__ kws,
                                                     _Float16* __restrict__ vtws) {
  __shared__ __align__(16) float As[32 * 64];         // 8 KB, swizzled 16B units
  __shared__ __align__(16) _Float16 Bs[192 * 64];     // 24 KB, swizzled 16B units
  const int tid = threadIdx.x;
  const int wave = tid >> 6;
  const int lane = tid & 63;
  const int quad = lane >> 4;
  const int ln = lane & 15;
  const int t0 = blockIdx.x * 32;

  f32x4 acc[2][3];
#pragma unroll
  for (int mt = 0; mt < 2; ++mt)
#pragma unroll
    for (int nt = 0; nt < 3; ++nt) acc[mt][nt] = (f32x4){0.f, 0.f, 0.f, 0.f};

  // precompute staging addresses (loop-invariant parts)
  // A: 512 units of 16B; wave handles 64-unit (1KB) stripes
  int aU[2], aRow[2], aC[2];
#pragma unroll
  for (int i = 0; i < 2; ++i) {
    aU[i] = (i * 4 + wave) * 64 + lane;
    aRow[i] = aU[i] >> 4;
    aC[i] = (aU[i] & 15) ^ (aRow[i] & 15);
  }
  int bU[6], bN[6], bS8[6];
#pragma unroll
  for (int i = 0; i < 6; ++i) {
    bU[i] = (i * 4 + wave) * 64 + lane;
    bN[i] = bU[i] >> 3;
    bS8[i] = (bU[i] & 7) ^ (bN[i] & 7);
  }

  for (int kc = 0; kc < 16; ++kc) {
    // stage A (fp32): global x[(t0+row)*1024 + kc*64 + c*4 ..+3] -> unit aU
#pragma unroll
    for (int i = 0; i < 2; ++i)
      glds16(x + (size_t)(t0 + aRow[i]) * 1024 + kc * 64 + aC[i] * 4,
             &As[((i * 4 + wave) * 64) * 4]);
    // stage B (f16): wt[n*1024 + kc*64 + s8*8 ..+7] -> unit bU
#pragma unroll
    for (int i = 0; i < 6; ++i)
      glds16(wt + (size_t)bN[i] * 1024 + kc * 64 + bS8[i] * 8,
             &Bs[((i * 4 + wave) * 64) * 8]);
    __syncthreads();

#pragma unroll
    for (int s = 0; s < 2; ++s) {
      half8 av[2];
#pragma unroll
      for (int mt = 0; mt < 2; ++mt) {
        const int r = mt * 16 + ln;
        const int c0 = s * 8 + quad * 2;
        f32x4 u0 = *(const f32x4*)&As[(r * 16 + (c0 ^ ln)) * 4];
        f32x4 u1 = *(const f32x4*)&As[(r * 16 + ((c0 + 1) ^ ln)) * 4];
        union { fp16x2 p[4]; half8 v; } a;
        a.p[0] = __builtin_amdgcn_cvt_pkrtz(u0[0], u0[1]);
        a.p[1] = __builtin_amdgcn_cvt_pkrtz(u0[2], u0[3]);
        a.p[2] = __builtin_amdgcn_cvt_pkrtz(u1[0], u1[1]);
        a.p[3] = __builtin_amdgcn_cvt_pkrtz(u1[2], u1[3]);
        av[mt] = a.v;
      }
#pragma unroll
      for (int nt = 0; nt < 3; ++nt) {
        const int n = wave * 48 + nt * 16 + ln;
        const int s8 = s * 4 + quad;
        half8 b = *(const half8*)&Bs[(n * 8 + (s8 ^ (ln & 7))) * 8];
#pragma unroll
        for (int mt = 0; mt < 2; ++mt)
          acc[mt][nt] = __builtin_amdgcn_mfma_f32_16x16x32_f16(av[mt], b, acc[mt][nt], 0, 0, 0);
      }
    }
    __syncthreads();
  }

  // Epilogue: C/D layout row = quad*4+r, col = ln (within tile)
#pragma unroll
  for (int mt = 0; mt < 2; ++mt) {
    const int trow0 = t0 + mt * 16 + quad * 4;
#pragma unroll
    for (int nt = 0; nt < 3; ++nt) {
      const int c = wave * 48 + nt * 16 + ln;
      const f32x4 a = acc[mt][nt];
      if (c < 64) {
#pragma unroll
        for (int r = 0; r < 4; ++r)
          qws[(size_t)(trow0 + r) * 64 + c] = (_Float16)(a[r] * 0.18033688011112042f);
      } else if (c < 128) {
        // interleaved K rows: within each 32-block, even keys -> 0..15, odd -> 16..31
#pragma unroll
        for (int r = 0; r < 4; ++r) {
          const int t = trow0 + r;
          const int pos = (t & ~31) | (((t & 31) >> 1) + ((t & 1) << 4));
          kws[(size_t)pos * 64 + (c - 64)] = (_Float16)a[r];
        }
      } else {
        const int h = c - 128;
        const int bb = trow0 >> 11;   // batch
        const int ti = trow0 & 2047;  // t within batch (multiple of 4)
        union { _Float16 h4[4]; short4 s; } u;
#pragma unroll
        for (int r = 0; r < 4; ++r) u.h4[r] = (_Float16)a[r];
        *(short4*)&vtws[(size_t)(bb * 64 + h) * 2048 + ti] = u.s;
      }
    }
  }
}

// ---------------------------------------------------------------------------
// Kernel 3: causal flash attention, fixed-max softmax (p = exp2(S-12)).
// 1024 blocks = (tile, batch), 256 thr = 4 waves; keys split 4 ways; K/V
// fragments prefetched one j ahead; packed P stores (K interleaved layout).
__global__ __launch_bounds__(256) void attn_kernel(const _Float16* __restrict__ qws,
                                                   const _Float16* __restrict__ kws,
                                                   const _Float16* __restrict__ vtws,
                                                   float* __restrict__ out) {
  __shared__ __align__(16) _Float16 plds[4 * 16 * 40];  // per-wave P tile (80B/row pad)
  __shared__ __align__(16) float Olds[4 * 16 * 64];
  __shared__ float llds[4 * 16];

  const int tid = threadIdx.x;
  const int wave = tid >> 6;
  const int lane = tid & 63;
  const int quad = lane >> 4;
  const int ln = lane & 15;
  const int tile = 127 - (blockIdx.x >> 3);  // biggest tiles dispatch first
  const int b = blockIdx.x & 7;
  const int t0 = tile * 16;
  const size_t bb = (size_t)b * 2048;
  _Float16* myp = plds + wave * 640;

  const float NEG_INF = -__builtin_inff();

  // key blocks of 32 covering keys 0..t0+15, split balanced across 4 waves
  const int nkb = (t0 + 47) >> 5;
  const int base = nkb >> 2;
  const int rem = nkb & 3;
  const int jb = wave * base + (wave < rem ? wave : rem);
  const int je = jb + base + (wave < rem ? 1 : 0);

  // Q fragments (A-operand): row m = ln, k = h
  const _Float16* qrow = qws + (bb + t0 + ln) * 64;
  half8 qf0 = *(const half8*)(qrow + quad * 8);
  half8 qf1 = *(const half8*)(qrow + 32 + quad * 8);

  float l[4] = {0.f, 0.f, 0.f, 0.f};
  f32x4 O[4];
#pragma unroll
  for (int h = 0; h < 4; ++h) O[h] = (f32x4){0.f, 0.f, 0.f, 0.f};

  const _Float16* kbase = kws + (bb + (size_t)jb * 32) * 64;
  const _Float16* vbase = vtws + (size_t)b * 131072 + jb * 32;
  half8 kf0, kf1, kf2, kf3, vf0, vf1, vf2, vf3;
  if (jb < je) {
    kf0 = *(const half8*)(kbase + ln * 64 + quad * 8);
    kf1 = *(const half8*)(kbase + ln * 64 + 32 + quad * 8);
    kf2 = *(const half8*)(kbase + (16 + ln) * 64 + quad * 8);
    kf3 = *(const half8*)(kbase + (16 + ln) * 64 + 32 + quad * 8);
    vf0 = *(const half8*)(vbase + (size_t)(ln) * 2048 + quad * 8);
    vf1 = *(const half8*)(vbase + (size_t)(16 + ln) * 2048 + quad * 8);
    vf2 = *(const half8*)(vbase + (size_t)(32 + ln) * 2048 + quad * 8);
    vf3 = *(const half8*)(vbase + (size_t)(48 + ln) * 2048 + quad * 8);
  }

  for (int j = jb; j < je; ++j) {
    const int k0 = j << 5;
    f32x4 S0 = (f32x4){0.f, 0.f, 0.f, 0.f};
    f32x4 S1 = (f32x4){0.f, 0.f, 0.f, 0.f};
    S0 = __builtin_amdgcn_mfma_f32_16x16x32_f16(qf0, kf0, S0, 0, 0, 0);
    S0 = __builtin_amdgcn_mfma_f32_16x16x32_f16(qf1, kf1, S0, 0, 0, 0);
    S1 = __builtin_amdgcn_mfma_f32_16x16x32_f16(qf0, kf2, S1, 0, 0, 0);
    S1 = __builtin_amdgcn_mfma_f32_16x16x32_f16(qf1, kf3, S1, 0, 0, 0);

    // prefetch next K block while softmax runs
    if (j + 1 < je) {
      kbase += 2048;
      kf0 = *(const half8*)(kbase + ln * 64 + quad * 8);
      kf1 = *(const half8*)(kbase + ln * 64 + 32 + quad * 8);
      kf2 = *(const half8*)(kbase + (16 + ln) * 64 + quad * 8);
      kf3 = *(const half8*)(kbase + (16 + ln) * 64 + 32 + quad * 8);
    }

    // S0 col ln = key k0+2*ln (even), S1 col ln = key k0+2*ln+1 (odd)
    if (k0 + 31 > t0) {
      const int key0 = k0 + 2 * ln;
#pragma unroll
      for (int r = 0; r < 4; ++r) {
        const int tq = t0 + quad * 4 + r;
        if (key0 > tq) S0[r] = NEG_INF;
        if (key0 + 1 > tq) S1[r] = NEG_INF;
      }
    }

#pragma unroll
    for (int r = 0; r < 4; ++r) {
      const float p0 = exp2f(S0[r] - 12.f);
      const float p1 = exp2f(S1[r] - 12.f);
      l[r] += p0 + p1;
      const int prow = quad * 4 + r;
      union { fp16x2 v; unsigned u; } pk;
      pk.v = __builtin_amdgcn_cvt_pkrtz(p0, p1);  // keys 2ln, 2ln+1
      *(unsigned*)&myp[prow * 40 + 2 * ln] = pk.u;
    }

    // P as A-operand: A[m=ln][k=quad*8+j] (wave-private LDS, in-order DS pipe)
    half8 pfr = *(const half8*)(myp + ln * 40 + quad * 8);
    O[0] = __builtin_amdgcn_mfma_f32_16x16x32_f16(pfr, vf0, O[0], 0, 0, 0);
    O[1] = __builtin_amdgcn_mfma_f32_16x16x32_f16(pfr, vf1, O[1], 0, 0, 0);
    O[2] = __builtin_amdgcn_mfma_f32_16x16x32_f16(pfr, vf2, O[2], 0, 0, 0);
    O[3] = __builtin_amdgcn_mfma_f32_16x16x32_f16(pfr, vf3, O[3], 0, 0, 0);

    if (j + 1 < je) {
      vbase += 32;
      vf0 = *(const half8*)(vbase + (size_t)(ln) * 2048 + quad * 8);
      vf1 = *(const half8*)(vbase + (size_t)(16 + ln) * 2048 + quad * 8);
      vf2 = *(const half8*)(vbase + (size_t)(32 + ln) * 2048 + quad * 8);
      vf3 = *(const half8*)(vbase + (size_t)(48 + ln) * 2048 + quad * 8);
    }
  }

  // reduce l across the 16 ln-lanes of each quad
#pragma unroll
  for (int r = 0; r < 4; ++r) {
    l[r] += __shfl_xor(l[r], 1);
    l[r] += __shfl_xor(l[r], 2);
    l[r] += __shfl_xor(l[r], 4);
    l[r] += __shfl_xor(l[r], 8);
  }

  // dump partials to LDS
#pragma unroll
  for (int r = 0; r < 4; ++r) {
    const int row = quad * 4 + r;
    if (ln == 0) llds[wave * 16 + row] = l[r];
#pragma unroll
    for (int h = 0; h < 4; ++h)
      Olds[wave * 1024 + row * 64 + h * 16 + ln] = O[h][r];
  }
  __syncthreads();

  // final 4-way sum + normalize + write: thread t -> row t>>4, cols (t&15)*4..+3
  {
    const int row = tid >> 4;
    const int col0 = (tid & 15) * 4;
    f32x4 s = (f32x4){0.f, 0.f, 0.f, 0.f};
    float ls = 0.f;
#pragma unroll
    for (int w = 0; w < 4; ++w) {
      s += *(const f32x4*)&Olds[w * 1024 + row * 64 + col0];
      ls += llds[w * 16 + row];
    }
    const float inv = 1.0f / ls;
    float4 o;
    o.x = s[0] * inv; o.y = s[1] * inv; o.z = s[2] * inv; o.w = s[3] * inv;
    *(float4*)&out[(bb + t0 + row) * 64 + col0] = o;
  }
}

// ---------------------------------------------------------------------------
extern "C" void kernel_launch(void* const* d_in, const int* in_sizes, int n_in,
                              void* d_out, int out_size, void* d_ws, size_t ws_size,
                              hipStream_t stream) {
  const float* x  = (const float*)d_in[0];
  const float* wq = (const float*)d_in[1];
  const float* wk = (const float*)d_in[2];
  const float* wv = (const float*)d_in[3];

  char* ws = (char*)d_ws;
  _Float16* wt   = (_Float16*)(ws + WT_OFF);
  _Float16* qws  = (_Float16*)(ws + Q_OFF);
  _Float16* kws  = (_Float16*)(ws + K_OFF);
  _Float16* vtws = (_Float16*)(ws + V_OFF);
  float* outp = (float*)d_out;

  wcvt_kernel<<<768, 256, 0, stream>>>(wq, wk, wv, wt);
  qkv_kernel<<<512, 256, 0, stream>>>(x, wt, qws, kws, vtws);
  attn_kernel<<<1024, 256, 0, stream>>>(qws, kws, vtws, outp);
}

// Round 6
// 148.074 us; speedup vs baseline: 1.3512x; 1.0318x over previous
//
#include <hip/hip_runtime.h>
#include <cstddef>

typedef _Float16 half8 __attribute__((ext_vector_type(8)));
typedef __fp16 fp16x2 __attribute__((ext_vector_type(2)));
typedef float f32x4 __attribute__((ext_vector_type(4)));

// Problem constants: B=8, T=2048, D=1024, H=64
// Workspace layout (bytes):
//   Wt  (f16, [192][1024], W^T concat q|k|v):      0
//   q   (f16, [16384][64], pre-scaled by 0.125*log2e)
//   k   (f16, [16384][64], rows INTERLEAVED within 32-blocks: even keys 0..15, odd 16..31)
//   vT  (f16, [8][64][2048])
#define WT_OFF 0
#define Q_OFF  393216
#define K_OFF  2490368
#define V_OFF  4587520

__device__ __forceinline__ void glds16(const void* g, const void* l) {
  __builtin_amdgcn_global_load_lds(
      (const __attribute__((address_space(1))) unsigned*)g,
      (__attribute__((address_space(3))) unsigned*)l, 16, 0, 0);
}

// ---------------------------------------------------------------------------
// Kernel 1: Wq|Wk|Wv ([1024][64] fp32) -> transposed f16 Wt[c][d].
// Coalesced reads, scattered 2B writes (fire-and-forget).
__global__ __launch_bounds__(256) void wcvt_kernel(const float* __restrict__ wq,
                                                   const float* __restrict__ wk,
                                                   const float* __restrict__ wv,
                                                   _Float16* __restrict__ wt) {
  int i = blockIdx.x * 256 + threadIdx.x;  // 0..65535 ; d = i>>6, c = i&63
  int d = i >> 6;
  int c = i & 63;
  wt[(size_t)c * 1024 + d] = (_Float16)wq[i];
  wt[(size_t)(64 + c) * 1024 + d] = (_Float16)wk[i];
  wt[(size_t)(128 + c) * 1024 + d] = (_Float16)wv[i];
}

// ---------------------------------------------------------------------------
// Kernel 2: QKV projection, m97-style (unchanged from R5).
__global__ __launch_bounds__(256, 2) void qkv_kernel(const float* __restrict__ x,
                                                     const _Float16* __restrict__ wt,
                                                     _Float16* __restrict__ qws,
                                                     _Float16* __restrict__ kws,
                                                     _Float16* __restrict__ vtws) {
  __shared__ __align__(16) float As[32 * 64];
  __shared__ __align__(16) _Float16 Bs[192 * 64];
  const int tid = threadIdx.x;
  const int wave = tid >> 6;
  const int lane = tid & 63;
  const int quad = lane >> 4;
  const int ln = lane & 15;
  const int t0 = blockIdx.x * 32;

  f32x4 acc[2][3];
#pragma unroll
  for (int mt = 0; mt < 2; ++mt)
#pragma unroll
    for (int nt = 0; nt < 3; ++nt) acc[mt][nt] = (f32x4){0.f, 0.f, 0.f, 0.f};

  int aU[2], aRow[2], aC[2];
#pragma unroll
  for (int i = 0; i < 2; ++i) {
    aU[i] = (i * 4 + wave) * 64 + lane;
    aRow[i] = aU[i] >> 4;
    aC[i] = (aU[i] & 15) ^ (aRow[i] & 15);
  }
  int bU[6], bN[6], bS8[6];
#pragma unroll
  for (int i = 0; i < 6; ++i) {
    bU[i] = (i * 4 + wave) * 64 + lane;
    bN[i] = bU[i] >> 3;
    bS8[i] = (bU[i] & 7) ^ (bN[i] & 7);
  }

  for (int kc = 0; kc < 16; ++kc) {
#pragma unroll
    for (int i = 0; i < 2; ++i)
      glds16(x + (size_t)(t0 + aRow[i]) * 1024 + kc * 64 + aC[i] * 4,
             &As[((i * 4 + wave) * 64) * 4]);
#pragma unroll
    for (int i = 0; i < 6; ++i)
      glds16(wt + (size_t)bN[i] * 1024 + kc * 64 + bS8[i] * 8,
             &Bs[((i * 4 + wave) * 64) * 8]);
    __syncthreads();

#pragma unroll
    for (int s = 0; s < 2; ++s) {
      half8 av[2];
#pragma unroll
      for (int mt = 0; mt < 2; ++mt) {
        const int r = mt * 16 + ln;
        const int c0 = s * 8 + quad * 2;
        f32x4 u0 = *(const f32x4*)&As[(r * 16 + (c0 ^ ln)) * 4];
        f32x4 u1 = *(const f32x4*)&As[(r * 16 + ((c0 + 1) ^ ln)) * 4];
        union { fp16x2 p[4]; half8 v; } a;
        a.p[0] = __builtin_amdgcn_cvt_pkrtz(u0[0], u0[1]);
        a.p[1] = __builtin_amdgcn_cvt_pkrtz(u0[2], u0[3]);
        a.p[2] = __builtin_amdgcn_cvt_pkrtz(u1[0], u1[1]);
        a.p[3] = __builtin_amdgcn_cvt_pkrtz(u1[2], u1[3]);
        av[mt] = a.v;
      }
#pragma unroll
      for (int nt = 0; nt < 3; ++nt) {
        const int n = wave * 48 + nt * 16 + ln;
        const int s8 = s * 4 + quad;
        half8 b = *(const half8*)&Bs[(n * 8 + (s8 ^ (ln & 7))) * 8];
#pragma unroll
        for (int mt = 0; mt < 2; ++mt)
          acc[mt][nt] = __builtin_amdgcn_mfma_f32_16x16x32_f16(av[mt], b, acc[mt][nt], 0, 0, 0);
      }
    }
    __syncthreads();
  }

#pragma unroll
  for (int mt = 0; mt < 2; ++mt) {
    const int trow0 = t0 + mt * 16 + quad * 4;
#pragma unroll
    for (int nt = 0; nt < 3; ++nt) {
      const int c = wave * 48 + nt * 16 + ln;
      const f32x4 a = acc[mt][nt];
      if (c < 64) {
#pragma unroll
        for (int r = 0; r < 4; ++r)
          qws[(size_t)(trow0 + r) * 64 + c] = (_Float16)(a[r] * 0.18033688011112042f);
      } else if (c < 128) {
#pragma unroll
        for (int r = 0; r < 4; ++r) {
          const int t = trow0 + r;
          const int pos = (t & ~31) | (((t & 31) >> 1) + ((t & 1) << 4));
          kws[(size_t)pos * 64 + (c - 64)] = (_Float16)a[r];
        }
      } else {
        const int h = c - 128;
        const int bb = trow0 >> 11;
        const int ti = trow0 & 2047;
        union { _Float16 h4[4]; short4 s; } u;
#pragma unroll
        for (int r = 0; r < 4; ++r) u.h4[r] = (_Float16)a[r];
        *(short4*)&vtws[(size_t)(bb * 64 + h) * 2048 + ti] = u.s;
      }
    }
  }
}

// ---------------------------------------------------------------------------
// Kernel 3: flash attention, block-cooperative LDS staging.
// 256 blocks x 256 thr. Block = (batch b, pair {63-p, p} of 32-query tiles),
// processed as two passes (uniform total work). Per pass: K-loop over 64-key
// chunks; K (interleaved rows) + V^T staged to double-buffered swizzled LDS
// via global_load_lds. Waves: qt = wave>>1 (16 queries), kh = wave&1 (32 of
// the 64 staged keys). Fixed-max softmax p=exp2(S-12) -> additive merge.
__global__ __launch_bounds__(256) void attn_kernel(const _Float16* __restrict__ qws,
                                                   const _Float16* __restrict__ kws,
                                                   const _Float16* __restrict__ vtws,
                                                   float* __restrict__ out) {
  __shared__ __align__(16) _Float16 Ks[2][64 * 64];   // 2 x 8 KB
  __shared__ __align__(16) _Float16 Vs[2][64 * 64];   // 2 x 8 KB
  __shared__ __align__(16) _Float16 plds[4 * 16 * 40];
  __shared__ __align__(16) float Olds[2][16 * 64];
  __shared__ float llds[2][16];

  const int tid = threadIdx.x;
  const int wave = tid >> 6;
  const int lane = tid & 63;
  const int quad = lane >> 4;
  const int ln = lane & 15;
  const int b = blockIdx.x & 7;
  const int pr = blockIdx.x >> 3;  // pair index 0..31
  const size_t bb = (size_t)b * 2048;
  const int qt = wave >> 1;  // q-tile within 32-q block
  const int kh = wave & 1;   // key-half within 64-key chunk
  _Float16* myp = plds + wave * 640;

  const float NEG_INF = -__builtin_inff();

  // staging address precompute (unit = 16B; swizzle c8 ^= row&7)
  int kR[2], kC8[2], vH[2], vC8[2];
#pragma unroll
  for (int i = 0; i < 2; ++i) {
    const int u = i * 256 + wave * 64 + lane;
    kR[i] = u >> 3;
    kC8[i] = (u & 7) ^ (kR[i] & 7);
    vH[i] = u >> 3;
    vC8[i] = (u & 7) ^ (vH[i] & 7);
  }

  for (int pass = 0; pass < 2; ++pass) {
    const int t = (pass == 0) ? (63 - pr) : pr;
    const int t0 = t * 32;
    const int nch = (32 * t + 95) >> 6;  // 64-key chunks covering keys 0..32t+31

    // Q fragments for this pass (A-operand: row m=ln, k=h)
    const _Float16* qrow = qws + (bb + t0 + qt * 16 + ln) * 64;
    const half8 qf0 = *(const half8*)(qrow + quad * 8);
    const half8 qf1 = *(const half8*)(qrow + 32 + quad * 8);

    float l[4] = {0.f, 0.f, 0.f, 0.f};
    f32x4 O[4];
#pragma unroll
    for (int h = 0; h < 4; ++h) O[h] = (f32x4){0.f, 0.f, 0.f, 0.f};

    // stage chunk 0 into buffer 0
#pragma unroll
    for (int i = 0; i < 2; ++i) {
      glds16(kws + (bb + kR[i]) * 64 + kC8[i] * 8,
             &Ks[0][(i * 256 + wave * 64) * 8]);
      glds16(vtws + (size_t)(b * 64 + vH[i]) * 2048 + vC8[i] * 8,
             &Vs[0][(i * 256 + wave * 64) * 8]);
    }
    __syncthreads();

    for (int c = 0; c < nch; ++c) {
      const int k0 = c * 64;
      const int buf = c & 1;
      if (c + 1 < nch) {
        const int nk0 = k0 + 64;
        const int nb = (c + 1) & 1;
#pragma unroll
        for (int i = 0; i < 2; ++i) {
          glds16(kws + (bb + nk0 + kR[i]) * 64 + kC8[i] * 8,
                 &Ks[nb][(i * 256 + wave * 64) * 8]);
          glds16(vtws + (size_t)(b * 64 + vH[i]) * 2048 + nk0 + vC8[i] * 8,
                 &Vs[nb][(i * 256 + wave * 64) * 8]);
        }
      }

      // ---- compute chunk c from buf ----
      // K fragments: LDS row = kh*32 + s*16 + ln, h-group = hs*32 + quad*8
      const int rb = kh * 32 + ln;
      half8 kf00 = *(const half8*)&Ks[buf][(rb * 8 + ((0 + quad) ^ (ln & 7))) * 8];
      half8 kf01 = *(const half8*)&Ks[buf][(rb * 8 + ((4 + quad) ^ (ln & 7))) * 8];
      half8 kf10 = *(const half8*)&Ks[buf][((rb + 16) * 8 + ((0 + quad) ^ (ln & 7))) * 8];
      half8 kf11 = *(const half8*)&Ks[buf][((rb + 16) * 8 + ((4 + quad) ^ (ln & 7))) * 8];

      f32x4 S0 = (f32x4){0.f, 0.f, 0.f, 0.f};
      f32x4 S1 = (f32x4){0.f, 0.f, 0.f, 0.f};
      S0 = __builtin_amdgcn_mfma_f32_16x16x32_f16(qf0, kf00, S0, 0, 0, 0);
      S0 = __builtin_amdgcn_mfma_f32_16x16x32_f16(qf1, kf01, S0, 0, 0, 0);
      S1 = __builtin_amdgcn_mfma_f32_16x16x32_f16(qf0, kf10, S1, 0, 0, 0);
      S1 = __builtin_amdgcn_mfma_f32_16x16x32_f16(qf1, kf11, S1, 0, 0, 0);

      // causal mask (interleaved keys): S0 col ln -> key k0c+2ln, S1 -> +1
      const int k0c = k0 + kh * 32;
      if (k0c + 31 > t0 + qt * 16) {
        const int key0 = k0c + 2 * ln;
#pragma unroll
        for (int r = 0; r < 4; ++r) {
          const int tq = t0 + qt * 16 + quad * 4 + r;
          if (key0 > tq) S0[r] = NEG_INF;
          if (key0 + 1 > tq) S1[r] = NEG_INF;
        }
      }

#pragma unroll
      for (int r = 0; r < 4; ++r) {
        const float p0 = exp2f(S0[r] - 12.f);
        const float p1 = exp2f(S1[r] - 12.f);
        l[r] += p0 + p1;
        union { fp16x2 v; unsigned u; } pk;
        pk.v = __builtin_amdgcn_cvt_pkrtz(p0, p1);
        *(unsigned*)&myp[(quad * 4 + r) * 40 + 2 * ln] = pk.u;
      }

      // P as A-operand (wave-private LDS round trip, in-order DS pipe)
      half8 pfr = *(const half8*)(myp + ln * 40 + quad * 8);
#pragma unroll
      for (int ht = 0; ht < 4; ++ht) {
        const int h = ht * 16 + ln;
        half8 vf = *(const half8*)&Vs[buf][(h * 8 + ((kh * 4 + quad) ^ (ln & 7))) * 8];
        O[ht] = __builtin_amdgcn_mfma_f32_16x16x32_f16(pfr, vf, O[ht], 0, 0, 0);
      }
      __syncthreads();
    }

    // reduce l across the 16 ln-lanes of each quad
#pragma unroll
    for (int r = 0; r < 4; ++r) {
      l[r] += __shfl_xor(l[r], 1);
      l[r] += __shfl_xor(l[r], 2);
      l[r] += __shfl_xor(l[r], 4);
      l[r] += __shfl_xor(l[r], 8);
    }

    // 2-way merge across key-halves (additive thanks to fixed shift)
    if (kh == 1) {
#pragma unroll
      for (int r = 0; r < 4; ++r) {
        const int row = quad * 4 + r;
        if (ln == 0) llds[qt][row] = l[r];
#pragma unroll
        for (int ht = 0; ht < 4; ++ht)
          Olds[qt][row * 64 + ht * 16 + ln] = O[ht][r];
      }
    }
    __syncthreads();
    if (kh == 0) {
#pragma unroll
      for (int r = 0; r < 4; ++r) {
        const int row = quad * 4 + r;
        const float inv = 1.0f / (l[r] + llds[qt][row]);
        float* orow = out + (bb + t0 + qt * 16 + row) * 64;
#pragma unroll
        for (int ht = 0; ht < 4; ++ht)
          orow[ht * 16 + ln] = (O[ht][r] + Olds[qt][row * 64 + ht * 16 + ln]) * inv;
      }
    }
    __syncthreads();
  }
}

// ---------------------------------------------------------------------------
extern "C" void kernel_launch(void* const* d_in, const int* in_sizes, int n_in,
                              void* d_out, int out_size, void* d_ws, size_t ws_size,
                              hipStream_t stream) {
  const float* x  = (const float*)d_in[0];
  const float* wq = (const float*)d_in[1];
  const float* wk = (const float*)d_in[2];
  const float* wv = (const float*)d_in[3];

  char* ws = (char*)d_ws;
  _Float16* wt   = (_Float16*)(ws + WT_OFF);
  _Float16* qws  = (_Float16*)(ws + Q_OFF);
  _Float16* kws  = (_Float16*)(ws + K_OFF);
  _Float16* vtws = (_Float16*)(ws + V_OFF);
  float* outp = (float*)d_out;

  wcvt_kernel<<<256, 256, 0, stream>>>(wq, wk, wv, wt);
  qkv_kernel<<<512, 256, 0, stream>>>(x, wt, qws, kws, vtws);
  attn_kernel<<<256, 256, 0, stream>>>(qws, kws, vtws, outp);
}

// Round 8
// 140.884 us; speedup vs baseline: 1.4201x; 1.0510x over previous
//
#include <hip/hip_runtime.h>
#include <cstddef>

typedef _Float16 half8 __attribute__((ext_vector_type(8)));
typedef __fp16 fp16x2 __attribute__((ext_vector_type(2)));
typedef float f32x4 __attribute__((ext_vector_type(4)));

// Problem constants: B=8, T=2048, D=1024, H=64
// Workspace layout (bytes):
//   Wt  (f16, [192][1024], W^T concat q|k|v):      0
//   q   (f16, [16384][64], pre-scaled by 0.125*log2e)
//   k   (f16, [16384][64], rows INTERLEAVED within 32-blocks: even keys 0..15, odd 16..31)
//   vT  (f16, [8][64][2048], plain t order)
#define WT_OFF 0
#define Q_OFF  393216
#define K_OFF  2490368
#define V_OFF  4587520

__device__ __forceinline__ void glds16(const void* g, const void* l) {
  __builtin_amdgcn_global_load_lds(
      (const __attribute__((address_space(1))) unsigned*)g,
      (__attribute__((address_space(3))) unsigned*)l, 16, 0, 0);
}

// ---------------------------------------------------------------------------
// Kernel 1: convert Wq|Wk|Wv (each [1024][64] fp32) into transposed f16 Wt[c][d]
__global__ __launch_bounds__(256) void wcvt_kernel(const float* __restrict__ wq,
                                                   const float* __restrict__ wk,
                                                   const float* __restrict__ wv,
                                                   _Float16* __restrict__ wt) {
  int idx = blockIdx.x * 256 + threadIdx.x;  // idx = c*1024 + d, 196608 total
  int c = idx >> 10;
  int d = idx & 1023;
  float v;
  if (c < 64)       v = wq[d * 64 + c];
  else if (c < 128) v = wk[d * 64 + (c - 64)];
  else              v = wv[d * 64 + (c - 128)];
  wt[idx] = (_Float16)v;
}

// ---------------------------------------------------------------------------
// Kernel 2: QKV projection, m97-style + double-buffered pipelined staging
// (prefetch(kc+1) -> compute(kc) -> sync; same rhythm as the R6-proven attn
// loop). Epilogue: q scaled, K interleaved, V^T plain short4 (R5-proven).
__global__ __launch_bounds__(256, 2) void qkv_kernel(const float* __restrict__ x,
                                                     const _Float16* __restrict__ wt,
                                                     _Float16* __restrict__ qws,
                                                     _Float16* __restrict__ kws,
                                                     _Float16* __restrict__ vtws) {
  __shared__ __align__(16) float As[2][32 * 64];      // 2 x 8 KB
  __shared__ __align__(16) _Float16 Bs[2][192 * 64];  // 2 x 24 KB
  const int tid = threadIdx.x;
  const int wave = tid >> 6;
  const int lane = tid & 63;
  const int quad = lane >> 4;
  const int ln = lane & 15;
  const int t0 = blockIdx.x * 32;

  f32x4 acc[2][3];
#pragma unroll
  for (int mt = 0; mt < 2; ++mt)
#pragma unroll
    for (int nt = 0; nt < 3; ++nt) acc[mt][nt] = (f32x4){0.f, 0.f, 0.f, 0.f};

  int aRow[2], aC[2];
#pragma unroll
  for (int i = 0; i < 2; ++i) {
    const int u = (i * 4 + wave) * 64 + lane;
    aRow[i] = u >> 4;
    aC[i] = (u & 15) ^ (aRow[i] & 15);
  }
  int bN[6], bS8[6];
#pragma unroll
  for (int i = 0; i < 6; ++i) {
    const int u = (i * 4 + wave) * 64 + lane;
    bN[i] = u >> 3;
    bS8[i] = (u & 7) ^ (bN[i] & 7);
  }

  // prologue: stage chunk 0 into buffer 0
#pragma unroll
  for (int i = 0; i < 2; ++i)
    glds16(x + (size_t)(t0 + aRow[i]) * 1024 + aC[i] * 4, &As[0][((i * 4 + wave) * 64) * 4]);
#pragma unroll
  for (int i = 0; i < 6; ++i)
    glds16(wt + (size_t)bN[i] * 1024 + bS8[i] * 8, &Bs[0][((i * 4 + wave) * 64) * 8]);
  __syncthreads();

  for (int kc = 0; kc < 16; ++kc) {
    const int buf = kc & 1;
    if (kc + 1 < 16) {
      const int nb = buf ^ 1;
#pragma unroll
      for (int i = 0; i < 2; ++i)
        glds16(x + (size_t)(t0 + aRow[i]) * 1024 + (kc + 1) * 64 + aC[i] * 4,
               &As[nb][((i * 4 + wave) * 64) * 4]);
#pragma unroll
      for (int i = 0; i < 6; ++i)
        glds16(wt + (size_t)bN[i] * 1024 + (kc + 1) * 64 + bS8[i] * 8,
               &Bs[nb][((i * 4 + wave) * 64) * 8]);
    }

#pragma unroll
    for (int s = 0; s < 2; ++s) {
      half8 av[2];
#pragma unroll
      for (int mt = 0; mt < 2; ++mt) {
        const int r = mt * 16 + ln;
        const int c0 = s * 8 + quad * 2;
        f32x4 u0 = *(const f32x4*)&As[buf][(r * 16 + (c0 ^ ln)) * 4];
        f32x4 u1 = *(const f32x4*)&As[buf][(r * 16 + ((c0 + 1) ^ ln)) * 4];
        union { fp16x2 p[4]; half8 v; } a;
        a.p[0] = __builtin_amdgcn_cvt_pkrtz(u0[0], u0[1]);
        a.p[1] = __builtin_amdgcn_cvt_pkrtz(u0[2], u0[3]);
        a.p[2] = __builtin_amdgcn_cvt_pkrtz(u1[0], u1[1]);
        a.p[3] = __builtin_amdgcn_cvt_pkrtz(u1[2], u1[3]);
        av[mt] = a.v;
      }
#pragma unroll
      for (int nt = 0; nt < 3; ++nt) {
        const int n = wave * 48 + nt * 16 + ln;
        const int s8 = s * 4 + quad;
        half8 b = *(const half8*)&Bs[buf][(n * 8 + (s8 ^ (ln & 7))) * 8];
#pragma unroll
        for (int mt = 0; mt < 2; ++mt)
          acc[mt][nt] = __builtin_amdgcn_mfma_f32_16x16x32_f16(av[mt], b, acc[mt][nt], 0, 0, 0);
      }
    }
    __syncthreads();
  }

  // Epilogue (R5-proven): C/D layout row = quad*4+r, col = ln
#pragma unroll
  for (int mt = 0; mt < 2; ++mt) {
    const int trow0 = t0 + mt * 16 + quad * 4;
#pragma unroll
    for (int nt = 0; nt < 3; ++nt) {
      const int c = wave * 48 + nt * 16 + ln;
      const f32x4 a = acc[mt][nt];
      if (c < 64) {
#pragma unroll
        for (int r = 0; r < 4; ++r)
          qws[(size_t)(trow0 + r) * 64 + c] = (_Float16)(a[r] * 0.18033688011112042f);
      } else if (c < 128) {
        // K rows interleaved within 32-blocks: even keys -> 0..15, odd -> 16..31
#pragma unroll
        for (int r = 0; r < 4; ++r) {
          const int t = trow0 + r;
          const int pos = (t & ~31) | (((t & 31) >> 1) + ((t & 1) << 4));
          kws[(size_t)pos * 64 + (c - 64)] = (_Float16)a[r];
        }
      } else {
        const int h = c - 128;
        const int bbb = trow0 >> 11;   // batch
        const int ti = trow0 & 2047;   // t within batch (multiple of 4)
        union { _Float16 h4[4]; short4 s; } u;
#pragma unroll
        for (int r = 0; r < 4; ++r) u.h4[r] = (_Float16)a[r];
        *(short4*)&vtws[(size_t)(bbb * 64 + h) * 2048 + ti] = u.s;
      }
    }
  }
}

// ---------------------------------------------------------------------------
// Kernel 3: flash attention (R6-proven body). 512 blocks x 256 thr, one 32-q
// tile per block, heavy tiles dispatched first (pairs heavy+light per CU ->
// ~2 blocks/CU, barrier drains overlap). Waves: qt = wave>>1 (16 queries),
// kh = wave&1 (32 of the 64 staged keys). K interleaved, V plain.
// Fixed-max softmax p = exp2(S-12); additive merge via dedicated LDS.
__global__ __launch_bounds__(256, 2) void attn_kernel(const _Float16* __restrict__ qws,
                                                      const _Float16* __restrict__ kws,
                                                      const _Float16* __restrict__ vtws,
                                                      float* __restrict__ out) {
  __shared__ __align__(16) _Float16 Ks[2][64 * 64];   // 2 x 8 KB
  __shared__ __align__(16) _Float16 Vs[2][64 * 64];   // 2 x 8 KB
  __shared__ __align__(16) _Float16 plds[4 * 16 * 40];
  __shared__ __align__(16) float Olds[2][16 * 64];
  __shared__ float llds[2][16];

  const int tid = threadIdx.x;
  const int wave = tid >> 6;
  const int lane = tid & 63;
  const int quad = lane >> 4;
  const int ln = lane & 15;
  const int b = blockIdx.x & 7;
  const int tile = 63 - (blockIdx.x >> 3);  // heavy-first
  const int t0 = tile * 32;
  const size_t bb = (size_t)b * 2048;
  const int qt = wave >> 1;
  const int kh = wave & 1;
  _Float16* myp = plds + wave * 640;

  const float NEG_INF = -__builtin_inff();

  // staging address precompute (unit = 16B; swizzle c8 ^= row&7)
  int sR[2], sC8[2];
#pragma unroll
  for (int i = 0; i < 2; ++i) {
    const int u = i * 256 + wave * 64 + lane;
    sR[i] = u >> 3;
    sC8[i] = (u & 7) ^ (sR[i] & 7);
  }

  const int nch = (t0 + 95) >> 6;  // 64-key chunks covering keys 0..t0+31

  const _Float16* qrow = qws + (bb + t0 + qt * 16 + ln) * 64;
  const half8 qf0 = *(const half8*)(qrow + quad * 8);
  const half8 qf1 = *(const half8*)(qrow + 32 + quad * 8);

  float l[4] = {0.f, 0.f, 0.f, 0.f};
  f32x4 O[4];
#pragma unroll
  for (int h = 0; h < 4; ++h) O[h] = (f32x4){0.f, 0.f, 0.f, 0.f};

  // stage chunk 0 into buffer 0
#pragma unroll
  for (int i = 0; i < 2; ++i) {
    glds16(kws + (bb + sR[i]) * 64 + sC8[i] * 8, &Ks[0][(i * 256 + wave * 64) * 8]);
    glds16(vtws + (size_t)(b * 64 + sR[i]) * 2048 + sC8[i] * 8,
           &Vs[0][(i * 256 + wave * 64) * 8]);
  }
  __syncthreads();

  for (int c = 0; c < nch; ++c) {
    const int k0 = c * 64;
    const int buf = c & 1;
    if (c + 1 < nch) {
      const int nb = buf ^ 1;
#pragma unroll
      for (int i = 0; i < 2; ++i) {
        glds16(kws + (bb + k0 + 64 + sR[i]) * 64 + sC8[i] * 8,
               &Ks[nb][(i * 256 + wave * 64) * 8]);
        glds16(vtws + (size_t)(b * 64 + sR[i]) * 2048 + k0 + 64 + sC8[i] * 8,
               &Vs[nb][(i * 256 + wave * 64) * 8]);
      }
    }

    // ---- compute chunk c: this wave handles chunk rows kh*32 .. +31 ----
    const int rb = kh * 32 + ln;
    half8 kf00 = *(const half8*)&Ks[buf][(rb * 8 + ((0 + quad) ^ (ln & 7))) * 8];
    half8 kf01 = *(const half8*)&Ks[buf][(rb * 8 + ((4 + quad) ^ (ln & 7))) * 8];
    half8 kf10 = *(const half8*)&Ks[buf][((rb + 16) * 8 + ((0 + quad) ^ (ln & 7))) * 8];
    half8 kf11 = *(const half8*)&Ks[buf][((rb + 16) * 8 + ((4 + quad) ^ (ln & 7))) * 8];

    f32x4 S0 = (f32x4){0.f, 0.f, 0.f, 0.f};
    f32x4 S1 = (f32x4){0.f, 0.f, 0.f, 0.f};
    S0 = __builtin_amdgcn_mfma_f32_16x16x32_f16(qf0, kf00, S0, 0, 0, 0);
    S0 = __builtin_amdgcn_mfma_f32_16x16x32_f16(qf1, kf01, S0, 0, 0, 0);
    S1 = __builtin_amdgcn_mfma_f32_16x16x32_f16(qf0, kf10, S1, 0, 0, 0);
    S1 = __builtin_amdgcn_mfma_f32_16x16x32_f16(qf1, kf11, S1, 0, 0, 0);

    // causal mask (interleaved keys): S0 col ln -> key k0c+2ln, S1 -> +1
    const int k0c = k0 + kh * 32;
    if (k0c + 31 > t0 + qt * 16) {
      const int key0 = k0c + 2 * ln;
#pragma unroll
      for (int r = 0; r < 4; ++r) {
        const int tq = t0 + qt * 16 + quad * 4 + r;
        if (key0 > tq) S0[r] = NEG_INF;
        if (key0 + 1 > tq) S1[r] = NEG_INF;
      }
    }

#pragma unroll
    for (int r = 0; r < 4; ++r) {
      const float p0 = exp2f(S0[r] - 12.f);
      const float p1 = exp2f(S1[r] - 12.f);
      l[r] += p0 + p1;
      union { fp16x2 v; unsigned u; } pk;
      pk.v = __builtin_amdgcn_cvt_pkrtz(p0, p1);  // keys k0c+2ln, +1 -> P cols 2ln, 2ln+1
      *(unsigned*)&myp[(quad * 4 + r) * 40 + 2 * ln] = pk.u;
    }

    // P as A-operand (wave-private LDS round trip)
    half8 pfr = *(const half8*)(myp + ln * 40 + quad * 8);
#pragma unroll
    for (int ht = 0; ht < 4; ++ht) {
      const int h = ht * 16 + ln;
      half8 vf = *(const half8*)&Vs[buf][(h * 8 + ((kh * 4 + quad) ^ (h & 7))) * 8];
      O[ht] = __builtin_amdgcn_mfma_f32_16x16x32_f16(pfr, vf, O[ht], 0, 0, 0);
    }
    __syncthreads();
  }

  // reduce l across the 16 ln-lanes of each quad
#pragma unroll
  for (int r = 0; r < 4; ++r) {
    l[r] += __shfl_xor(l[r], 1);
    l[r] += __shfl_xor(l[r], 2);
    l[r] += __shfl_xor(l[r], 4);
    l[r] += __shfl_xor(l[r], 8);
  }

  // 2-way merge across key-halves (additive thanks to fixed shift)
  if (kh == 1) {
#pragma unroll
    for (int r = 0; r < 4; ++r) {
      const int row = quad * 4 + r;
      if (ln == 0) llds[qt][row] = l[r];
#pragma unroll
      for (int ht = 0; ht < 4; ++ht)
        Olds[qt][row * 64 + ht * 16 + ln] = O[ht][r];
    }
  }
  __syncthreads();
  if (kh == 0) {
#pragma unroll
    for (int r = 0; r < 4; ++r) {
      const int row = quad * 4 + r;
      const float inv = 1.0f / (l[r] + llds[qt][row]);
      float* orow = out + (bb + t0 + qt * 16 + row) * 64;
#pragma unroll
      for (int ht = 0; ht < 4; ++ht)
        orow[ht * 16 + ln] = (O[ht][r] + Olds[qt][row * 64 + ht * 16 + ln]) * inv;
    }
  }
}

// ---------------------------------------------------------------------------
extern "C" void kernel_launch(void* const* d_in, const int* in_sizes, int n_in,
                              void* d_out, int out_size, void* d_ws, size_t ws_size,
                              hipStream_t stream) {
  const float* x  = (const float*)d_in[0];
  const float* wq = (const float*)d_in[1];
  const float* wk = (const float*)d_in[2];
  const float* wv = (const float*)d_in[3];

  char* ws = (char*)d_ws;
  _Float16* wt   = (_Float16*)(ws + WT_OFF);
  _Float16* qws  = (_Float16*)(ws + Q_OFF);
  _Float16* kws  = (_Float16*)(ws + K_OFF);
  _Float16* vtws = (_Float16*)(ws + V_OFF);
  float* outp = (float*)d_out;

  wcvt_kernel<<<768, 256, 0, stream>>>(wq, wk, wv, wt);
  qkv_kernel<<<512, 256, 0, stream>>>(x, wt, qws, kws, vtws);
  attn_kernel<<<512, 256, 0, stream>>>(qws, kws, vtws, outp);
}